// Round 10
// baseline (493.971 us; speedup 1.0000x reference)
//
#include <hip/hip_runtime.h>
#include <hip/hip_bf16.h>

#define BB 512
#define SS 1024
#define NI 20
#define HH 64
#define NG 256   // 4*H
#define MB4 4    // batch-dirs per lstm block (1 cell per lane)
#define PAD 80   // h-row stride in f16
#define TROW 260 // x-table row stride (floats); [tok][unit][4tt], 16B rows

typedef unsigned short u16;
typedef unsigned int u32;
typedef unsigned long long u64;
typedef _Float16 f16;
typedef f16 f16x8 __attribute__((ext_vector_type(8)));
typedef float f32x4 __attribute__((ext_vector_type(4)));

#define LOG2E 1.4426950408889634f

__device__ __forceinline__ float bf2f(u16 b) { return __uint_as_float(((u32)b) << 16); }
// mode==1: data is bf16; mode==0: data is fp32
__device__ __forceinline__ float ldw(const void* p, int idx, int mode) {
  return mode ? bf2f(((const u16*)p)[idx]) : ((const float*)p)[idx];
}
__device__ __forceinline__ float frcp(float x) { return __builtin_amdgcn_rcpf(x); }
__device__ __forceinline__ float fexp2(float x) { return __builtin_amdgcn_exp2f(x); }

// ---- SINGLE fused kernel (r9 + kernel-2 elimination): blocks 0..255 = BiLSTM
// (r9-verbatim loop: parallel-K MFMA, d-state activation, b128 wx-table,
// compile-time SS trip count); blocks 256..767 = conv path, which after its
// conv (~30 us) SLEEP-POLLS per-group completion flags and then runs the fc
// tail (fc1->fc2->softmax->out) inline. This removes the 2nd kernel's launch +
// serialization gap (r9 evidence: total - lstm = 81 us >> the ~10-15 us of fc
// work). Producers: lstm block writes hout, per-thread threadfence, barrier,
// t0 releases flag[dir][group] (device-scope). Consumers: t0 acquire-polls
// both flags with s_sleep (no issue pressure on co-resident lstm waves),
// barrier, fence, fc. No deadlock: all 768 blocks co-resident at 3/CU
// (r8-verified), producers never wait. c2 stays in LDS (c2g global dropped).
// Flags zeroed by 1KB hipMemsetAsync (capture-safe). fc code lives ONLY in
// the conv branch path (r11/r12 lesson: keep the lstm path's codegen clean).
// Weights prescaled: i,f,o rows by -log2e, g rows by +2log2e (exp2-ready).
union __align__(16) SharedU {
  struct __align__(16) {                 // ---- lstm branch (~31.3 KB)
    float table[21 * TROW];              // 21.8 KB; doubles as extract staging
    f16 hbuf[2][MB4][PAD];
    short tok_s[SS * MB4];               // [pos][m], stores tok+1
  } l;
  struct __align__(16) {                 // ---- conv+fc branch (~29.8 KB)
    u32 stg[5120];                       // 20 KB extract staging
    float c1w[400];
    short tok_c[SS];                     // plain tok
    int redc[256];
    float pav[3][80];
    float avg[80];
    float cpart[2][100];
    float c2loc[100];                    // relu'd conv2 output (stays in LDS)
    float merged[228];
    float fpart[4][64];
    float fc1v[64];
    float f2p[2][64];
  } c;
};

__global__ __launch_bounds__(256)
void lstm_kernel(const void* in1,
                 const void* Wih_f, const void* Whh_f, const void* b_f,
                 const void* Wih_b, const void* Whh_b, const void* b_b,
                 const void* conv1_w, const void* conv2_w, const void* conv2_b,
                 const void* fc1_w, const void* fc1_b,
                 const void* fc2_w, const void* fc2_b,
                 int* flags, float* hout, void* out) {
  int bx = blockIdx.x;
  int t = threadIdx.x;

  __shared__ SharedU sh;
  __shared__ int mode_sh;

  // ---- mode probe: b_f read as bf16; fp32 shows wild exponents ----
  if (t == 0) mode_sh = 1;
  __syncthreads();
  {
    float v = bf2f(((const u16*)b_f)[t]);
    if (!(fabsf(v) < 1000.0f)) atomicAnd(&mode_sh, 0);
  }
  __syncthreads();
  int mode = mode_sh;

  if (bx < 256) {
    // ================= LSTM branch (r9 verbatim) =================
    auto& L = sh.l;
    int dir = bx >> 7;
    int b0 = (bx & 127) * MB4;
    int w = t >> 6, lane = t & 63, l = lane & 15, q = lane >> 4;
    int bsel = l >> 2;            // batch whose h this lane's A-row carries
    const void* Wih = dir ? Wih_b : Wih_f;
    const void* Whh = dir ? Whh_b : Whh_f;
    const void* bv  = dir ? b_b   : b_f;

    // ---- token extraction for this block's 4 batches (staged through table) ----
    for (int m = 0; m < MB4; ++m) {
      if (mode) {
        u32* st = (u32*)L.table;
        for (int k0 = 0; k0 < 4; ++k0) {
          const u32* src = (const u32*)in1 + ((size_t)(b0 + m) * SS + k0 * 256) * 10;
#pragma unroll
          for (int i = 0; i < 10; ++i) st[t + i * 256] = src[t + i * 256];  // coalesced
          __syncthreads();
          const u32* row = st + t * 10;
          int tok = -1;
#pragma unroll
          for (int ww = 0; ww < 10; ++ww) {
            u32 u = row[ww];
            if (u & 0xFFFFu) tok = 2 * ww;
            if (u >> 16)     tok = 2 * ww + 1;
          }
          L.tok_s[(k0 * 256 + t) * MB4 + m] = (short)(tok + 1);
          __syncthreads();
        }
      } else {
        float4* st = (float4*)L.table;
        for (int k0 = 0; k0 < 4; ++k0) {
          const float4* src = (const float4*)((const float*)in1 + ((size_t)(b0 + m) * SS + k0 * 256) * 20);
#pragma unroll
          for (int i = 0; i < 5; ++i) st[t + i * 256] = src[t + i * 256];  // coalesced 16B/lane
          __syncthreads();
          const float* row = (const float*)L.table + t * 20;
          int tok = -1;
#pragma unroll
          for (int ww = 0; ww < 20; ++ww)
            if (row[ww] != 0.f) tok = ww;
          L.tok_s[(k0 * 256 + t) * MB4 + m] = (short)(tok + 1);
          __syncthreads();
        }
      }
    }

    // ---- x-projection table: table[tok+1][u][tt] = scl_tt*(W_ih[64tt+u][tok]+b); row 0 = bias ----
    for (int idx = t; idx < 21 * 256; idx += 256) {
      int r = idx >> 8, g = idx & 255;
      float scl = ((g >> 6) == 2) ? (2.f * LOG2E) : (-LOG2E);
      float v = ldw(bv, g, mode);
      if (r > 0) v += ldw(Wih, g * NI + (r - 1), mode);
      L.table[r * TROW + (g & 63) * 4 + (g >> 6)] = scl * v;
    }
    // ---- W_hh B-fragments: n=lane&15 -> gate col (unit 16w+l, type tt), k=q*8+j ----
    f16x8 Bf[4][2];
#pragma unroll
    for (int tt = 0; tt < 4; ++tt) {
      float scl = (tt == 2) ? (2.f * LOG2E) : (-LOG2E);
      int g = 64 * tt + 16 * w + l;
#pragma unroll
      for (int kc = 0; kc < 2; ++kc) {
        f16x8 v;
#pragma unroll
        for (int j = 0; j < 8; ++j)
          v[j] = (f16)(scl * ldw(Whh, g * HH + kc * 32 + q * 8 + j, mode));
        Bf[tt][kc] = v;
      }
    }
    for (int idx = t; idx < 2 * MB4 * PAD; idx += 256)
      ((f16*)L.hbuf)[idx] = (f16)0.f;
    __syncthreads();

    float d_st = 0.f, hlast = 0.f;   // d = 2*log2e*c
    int jj = 16 * w + l;

    // x-pipeline prologue: wx for s=0 (regs), tok for s=1 (reg)
    f32x4 wxc;
    {
      int pos0 = dir ? (SS - 1) : 0;
      wxc = *(const f32x4*)&L.table[(int)L.tok_s[pos0 * MB4 + q] * TROW + jj * 4];
    }
    int tok1;
    {
      int pos1 = dir ? (SS - 2) : 1;
      tok1 = (int)L.tok_s[pos1 * MB4 + q];
    }

    const f32x4 Z = {0.f, 0.f, 0.f, 0.f};

#pragma unroll 2
    for (int s = 0; s < SS; ++s) {
      int p = s & 1;
      // critical path: h fragments (A[m=l][k=q*8+j] = h[bsel][k], 4x dup rows)
      f16x8 a0 = *(const f16x8*)&L.hbuf[p][bsel][q * 8];
      f16x8 a1 = *(const f16x8*)&L.hbuf[p][bsel][32 + q * 8];
      // off-path: wx prefetch for s+1 (single b128), tok fetch for s+2
      f32x4 wxn = *(const f32x4*)&L.table[tok1 * TROW + jj * 4];
      {
        int pos2 = (dir ? (SS - 3 - s) : (s + 2)) & (SS - 1);  // wrapped values unused
        tok1 = (int)L.tok_s[pos2 * MB4 + q];
      }

      // parallel-K MFMA pair per gate type (zero-C hoisted; one dependent MFMA
      // latency removed from the pole; gates assembled by scalar adds)
      f32x4 accA[4], accB[4];
#pragma unroll
      for (int tt = 0; tt < 4; ++tt)
        accA[tt] = __builtin_amdgcn_mfma_f32_16x16x32_f16(a0, Bf[tt][0], Z, 0, 0, 0);
#pragma unroll
      for (int tt = 0; tt < 4; ++tt)
        accB[tt] = __builtin_amdgcn_mfma_f32_16x16x32_f16(a1, Bf[tt][1], Z, 0, 0, 0);

      float g_i = accA[0][0] + accB[0][0] + wxc[0];
      float g_f = accA[1][0] + accB[1][0] + wxc[1];
      float g_g = accA[2][0] + accB[2][0] + wxc[2];
      float g_o = accA[3][0] + accB[3][0] + wxc[3];

      // d-state activation: Ei=e^-i, Ef=e^-f, Eo=e^-o, G=e^2g; F=sigma(f);
      // Itg=sigma(i)*tanh(g); d' = F*d + 2log2e*Itg; h = tanh(c)*sigma(o)
      {
        float Ei = fexp2(g_i);
        float Ef = fexp2(g_f);
        float G  = fexp2(g_g);
        float Eo = fexp2(g_o);
        float F   = frcp(Ef + 1.f);
        float Itg = (G - 1.f) * frcp((Ei + 1.f) * (G + 1.f));
        float dnew = fmaf(F, d_st, (2.f * LOG2E) * Itg);
        d_st = dnew;
        float C = fexp2(dnew);
        float hv = (C - 1.f) * frcp((Eo + 1.f) * (C + 1.f));
        hlast = hv;
        L.hbuf[p ^ 1][q][jj] = (f16)hv;
      }
      __syncthreads();
      wxc = wxn;
    }
    hout[(b0 + q) * 128 + dir * 64 + jj] = hlast;

    // ---- publish: all hout stores device-visible, then release the flag ----
    __threadfence();
    __syncthreads();
    if (t == 0)
      __hip_atomic_store(&flags[dir * 128 + (bx & 127)], 1,
                         __ATOMIC_RELEASE, __HIP_MEMORY_SCOPE_AGENT);

  } else {
    // ================= conv + fc branch (one batch) =================
    auto& C = sh.c;
    int b = bx - 256;
    // own extraction: plain tok per position + len
    int cnt = 0;
    if (mode) {
      for (int k0 = 0; k0 < 4; ++k0) {
        const u32* src = (const u32*)in1 + ((size_t)b * SS + k0 * 256) * 10;
#pragma unroll
        for (int i = 0; i < 10; ++i) C.stg[t + i * 256] = src[t + i * 256];  // coalesced
        __syncthreads();
        const u32* row = C.stg + t * 10;
        int tok = -1;
#pragma unroll
        for (int ww = 0; ww < 10; ++ww) {
          u32 u = row[ww];
          if (u & 0xFFFFu) tok = 2 * ww;
          if (u >> 16)     tok = 2 * ww + 1;
        }
        C.tok_c[k0 * 256 + t] = (short)tok;
        cnt += (tok >= 0);
        __syncthreads();
      }
    } else {
      float4* st = (float4*)C.stg;
      for (int k0 = 0; k0 < 4; ++k0) {
        const float4* src = (const float4*)((const float*)in1 + ((size_t)b * SS + k0 * 256) * 20);
#pragma unroll
        for (int i = 0; i < 5; ++i) st[t + i * 256] = src[t + i * 256];  // coalesced 16B/lane
        __syncthreads();
        const float* row = (const float*)C.stg + t * 20;
        int tok = -1;
#pragma unroll
        for (int ww = 0; ww < 20; ++ww)
          if (row[ww] != 0.f) tok = ww;
        C.tok_c[k0 * 256 + t] = (short)tok;
        cnt += (tok >= 0);
        __syncthreads();
      }
    }
    C.redc[t] = cnt;
    __syncthreads();
    for (int stp = 128; stp > 0; stp >>= 1) {
      if (t < stp) C.redc[t] += C.redc[t + stp];
      __syncthreads();
    }
    int len = C.redc[0];
    int bw = len >> 2;

    for (int i = t; i < 400; i += 256) C.c1w[i] = ldw(conv1_w, i, mode);
    __syncthreads();

    // ragged 4-bin mean: 240 threads = 80 (k,cc) units x 3 segments
    if (t < 240) {
      int seg = t / 80;
      int u = t - seg * 80;
      int k = u / 20, cc = u % 20;
      int base = k * bw;
      int s0 = base + (seg * bw) / 3;
      int s1 = base + ((seg + 1) * bw) / 3;
      float p0 = 0.f, p1 = 0.f, p2 = 0.f, p3 = 0.f;
      int s = s0;
      for (; s + 4 <= s1; s += 4) {
        // faithful torch reshape: flat f = s*20+cc of the [20,1024] map
        int f0 = s * 20 + cc, f1 = f0 + 20, f2 = f0 + 40, f3 = f0 + 60;
        int tk0 = C.tok_c[f0 & 1023];
        int tk1 = C.tok_c[f1 & 1023];
        int tk2 = C.tok_c[f2 & 1023];
        int tk3 = C.tok_c[f3 & 1023];
        if (tk0 >= 0) p0 += C.c1w[(f0 >> 10) * 20 + tk0];
        if (tk1 >= 0) p1 += C.c1w[(f1 >> 10) * 20 + tk1];
        if (tk2 >= 0) p2 += C.c1w[(f2 >> 10) * 20 + tk2];
        if (tk3 >= 0) p3 += C.c1w[(f3 >> 10) * 20 + tk3];
      }
      for (; s < s1; ++s) {
        int f = s * 20 + cc;
        int tk = C.tok_c[f & 1023];
        if (tk >= 0) p0 += C.c1w[(f >> 10) * 20 + tk];
      }
      C.pav[seg][u] = (p0 + p1) + (p2 + p3);
    }
    __syncthreads();
    if (t < 80) C.avg[t] = (C.pav[0][t] + C.pav[1][t] + C.pav[2][t]) / (float)bw;
    __syncthreads();

    // conv2: 200 threads = 100 outputs x 2 K-halves of 40
    if (t < 200) {
      int half = t / 100, o = t - half * 100;
      float dot = 0.f;
      int q0 = half * 40;
#pragma unroll 8
      for (int q = q0; q < q0 + 40; ++q)
        dot = fmaf(C.avg[q], ldw(conv2_w, o * 80 + q, mode), dot);
      C.cpart[half][o] = dot;
    }
    __syncthreads();
    if (t < 100) {
      float dot = C.cpart[0][t] + C.cpart[1][t] + ldw(conv2_b, t, mode);
      C.c2loc[t] = dot > 0.f ? dot : 0.f;  // relu'd, biased; stays in LDS
    }

    // ---- sleep-poll for this batch's two lstm producers ----
    int grp = b >> 2;
    if (t == 0) {
      for (;;) {
        int fa = __hip_atomic_load(&flags[grp],       __ATOMIC_ACQUIRE, __HIP_MEMORY_SCOPE_AGENT);
        int fb = __hip_atomic_load(&flags[128 + grp], __ATOMIC_ACQUIRE, __HIP_MEMORY_SCOPE_AGENT);
        if (fa && fb) break;
        __builtin_amdgcn_s_sleep(32);   // ~2k cycles; no issue pressure
      }
    }
    __syncthreads();
    __threadfence();   // acquire side: order hout reads after flag observation

    // ---- fc tail: merged = [hout | c2] -> fc1 -> fc2 -> softmax ----
    if (t < 128) C.merged[t] = hout[b * 128 + t];          // [h_fw | h_bw]
    else if (t < 228) C.merged[t] = C.c2loc[t - 128];
    __syncthreads();

    // fc1: 256 threads = 64 outputs x 4 K-chunks of 57
    {
      int o = t & 63, ch = t >> 6;
      float v = 0.f;
      int m0 = ch * 57;
#pragma unroll 8
      for (int m = m0; m < m0 + 57; ++m)
        v = fmaf(C.merged[m], ldw(fc1_w, o * 228 + m, mode), v);
      C.fpart[ch][o] = v;
    }
    __syncthreads();
    if (t < 64)
      C.fc1v[t] = C.fpart[0][t] + C.fpart[1][t] + C.fpart[2][t] + C.fpart[3][t] + ldw(fc1_b, t, mode);
    __syncthreads();

    // fc2: 128 threads compute products, tree-reduce
    if (t < 128) {
      int o = t >> 6, m = t & 63;
      C.f2p[o][m] = C.fc1v[m] * ldw(fc2_w, o * 64 + m, mode);
    }
    __syncthreads();
    for (int stp = 32; stp > 0; stp >>= 1) {
      if (t < 128) {
        int o = t >> 6, m = t & 63;
        if (m < stp) C.f2p[o][m] += C.f2p[o][m + stp];
      }
      __syncthreads();
    }
    if (t == 0) {
      float x0 = C.f2p[0][0] + ldw(fc2_b, 0, mode);
      float x1 = C.f2p[1][0] + ldw(fc2_b, 1, mode);
      float mx = fmaxf(x0, x1);
      float e0 = fexp2(LOG2E * (x0 - mx)), e1 = fexp2(LOG2E * (x1 - mx));
      float inv = frcp(e0 + e1);
      if (mode) {
        ((__hip_bfloat16*)out)[b * 2 + 0] = __float2bfloat16(e0 * inv);
        ((__hip_bfloat16*)out)[b * 2 + 1] = __float2bfloat16(e1 * inv);
      } else {
        ((float*)out)[b * 2 + 0] = e0 * inv;
        ((float*)out)[b * 2 + 1] = e1 * inv;
      }
    }
  }
}

extern "C" void kernel_launch(void* const* d_in, const int* in_sizes, int n_in,
                              void* d_out, int out_size, void* d_ws, size_t ws_size,
                              hipStream_t stream) {
  (void)in_sizes; (void)n_in; (void)out_size; (void)ws_size;
  char* ws = (char*)d_ws;
  int*   flags = (int*)ws;                                   // 1 KB (256 ints)
  float* hout  = (float*)(ws + 1024);                        // 256 KB

  hipMemsetAsync(flags, 0, 1024, stream);                    // capture-safe
  lstm_kernel<<<768, 256, 0, stream>>>(d_in[0],
                                       d_in[1], d_in[2], d_in[3],
                                       d_in[4], d_in[5], d_in[6],
                                       d_in[7], d_in[8], d_in[9],
                                       d_in[10], d_in[11], d_in[12], d_in[13],
                                       flags, hout, d_out);
}

// Round 11
// 440.067 us; speedup vs baseline: 1.1225x; 1.1225x over previous
//
#include <hip/hip_runtime.h>
#include <hip/hip_bf16.h>

#define BB 512
#define SS 1024
#define NI 20
#define HH 64
#define NG 256   // 4*H
#define MB4 4    // batch-dirs per lstm block (1 cell per lane)
#define PAD 80   // h-row stride in f16
#define TROW 260 // x-table row stride (floats); [tok][unit][4tt], 16B rows

typedef unsigned short u16;
typedef unsigned int u32;
typedef unsigned long long u64;
typedef _Float16 f16;
typedef f16 f16x8 __attribute__((ext_vector_type(8)));
typedef float f32x4 __attribute__((ext_vector_type(4)));

#define LOG2E 1.4426950408889634f

__device__ __forceinline__ float bf2f(u16 b) { return __uint_as_float(((u32)b) << 16); }
// mode==1: data is bf16; mode==0: data is fp32
__device__ __forceinline__ float ldw(const void* p, int idx, int mode) {
  return mode ? bf2f(((const u16*)p)[idx]) : ((const float*)p)[idx];
}
__device__ __forceinline__ float frcp(float x) { return __builtin_amdgcn_rcpf(x); }
__device__ __forceinline__ float fexp2(float x) { return __builtin_amdgcn_exp2f(x); }

// ---- SINGLE kernel, last-finisher election (r10 lesson: persistent sleeping
// consumers dilute producer issue 1.48x -- NOBODY waits while work remains).
// blocks 0..255 = BiLSTM (r9-verbatim loop). blocks 256..767 = conv path
// (r9-verified), which writes c2g + releases a per-batch flag and EXITS
// (CU freed, co-residency free per r8/r9). Each lstm block, after publishing
// hout, atomicAdd's its group counter; the SECOND finisher (its chain already
// done -> zero wall cost) runs the 4-batch fc tail inline: merged=[hout|c2] ->
// fc1 -> fc2 -> softmax -> out. Ordering: hout via acq-rel on the counter;
// c2g via acquire flags (set ~250 us earlier; poll expected 0 iterations).
// This deletes the 2nd kernel + its launch/serialization gap. fc uses LDS
// staging overlaid on the dead lstm tables (union). Weights prescaled:
// i,f,o rows by -log2e, g rows by +2log2e (exp2-ready gates).
union __align__(16) SharedU {
  struct __align__(16) {                 // ---- lstm branch (~31.3 KB)
    float table[21 * TROW];              // 21.8 KB; doubles as extract staging
    f16 hbuf[2][MB4][PAD];
    short tok_s[SS * MB4];               // [pos][m], stores tok+1
  } l;
  struct __align__(16) {                 // ---- conv branch (~27.2 KB)
    u32 stg[5120];                       // 20 KB extract staging
    float c1w[400];
    short tok_c[SS];                     // plain tok
    int redc[256];
    float pav[3][80];
    float avg[80];
    float cpart[2][100];
  } c;
  struct __align__(16) {                 // ---- fc epilogue (overlays dead lstm data)
    float merged[4][232];
    float fc1v[4][64];
    float f2[4][2];
  } f;
};

__global__ __launch_bounds__(256)
void lstm_kernel(const void* in1,
                 const void* Wih_f, const void* Whh_f, const void* b_f,
                 const void* Wih_b, const void* Whh_b, const void* b_b,
                 const void* conv1_w, const void* conv2_w, const void* conv2_b,
                 const void* fc1_w, const void* fc1_b,
                 const void* fc2_w, const void* fc2_b,
                 int* c2f, int* cnt, float* hout, float* c2g, void* out) {
  int bx = blockIdx.x;
  int t = threadIdx.x;

  __shared__ SharedU sh;
  __shared__ int mode_sh;
  __shared__ int elect_sh;

  // ---- mode probe: b_f read as bf16; fp32 shows wild exponents ----
  if (t == 0) mode_sh = 1;
  __syncthreads();
  {
    float v = bf2f(((const u16*)b_f)[t]);
    if (!(fabsf(v) < 1000.0f)) atomicAnd(&mode_sh, 0);
  }
  __syncthreads();
  int mode = mode_sh;

  if (bx < 256) {
    // ================= LSTM branch (r9 verbatim) =================
    auto& L = sh.l;
    int dir = bx >> 7;
    int b0 = (bx & 127) * MB4;
    int w = t >> 6, lane = t & 63, l = lane & 15, q = lane >> 4;
    int bsel = l >> 2;            // batch whose h this lane's A-row carries
    const void* Wih = dir ? Wih_b : Wih_f;
    const void* Whh = dir ? Whh_b : Whh_f;
    const void* bv  = dir ? b_b   : b_f;

    // ---- token extraction for this block's 4 batches (staged through table) ----
    for (int m = 0; m < MB4; ++m) {
      if (mode) {
        u32* st = (u32*)L.table;
        for (int k0 = 0; k0 < 4; ++k0) {
          const u32* src = (const u32*)in1 + ((size_t)(b0 + m) * SS + k0 * 256) * 10;
#pragma unroll
          for (int i = 0; i < 10; ++i) st[t + i * 256] = src[t + i * 256];  // coalesced
          __syncthreads();
          const u32* row = st + t * 10;
          int tok = -1;
#pragma unroll
          for (int ww = 0; ww < 10; ++ww) {
            u32 u = row[ww];
            if (u & 0xFFFFu) tok = 2 * ww;
            if (u >> 16)     tok = 2 * ww + 1;
          }
          L.tok_s[(k0 * 256 + t) * MB4 + m] = (short)(tok + 1);
          __syncthreads();
        }
      } else {
        float4* st = (float4*)L.table;
        for (int k0 = 0; k0 < 4; ++k0) {
          const float4* src = (const float4*)((const float*)in1 + ((size_t)(b0 + m) * SS + k0 * 256) * 20);
#pragma unroll
          for (int i = 0; i < 5; ++i) st[t + i * 256] = src[t + i * 256];  // coalesced 16B/lane
          __syncthreads();
          const float* row = (const float*)L.table + t * 20;
          int tok = -1;
#pragma unroll
          for (int ww = 0; ww < 20; ++ww)
            if (row[ww] != 0.f) tok = ww;
          L.tok_s[(k0 * 256 + t) * MB4 + m] = (short)(tok + 1);
          __syncthreads();
        }
      }
    }

    // ---- x-projection table: table[tok+1][u][tt] = scl_tt*(W_ih[64tt+u][tok]+b); row 0 = bias ----
    for (int idx = t; idx < 21 * 256; idx += 256) {
      int r = idx >> 8, g = idx & 255;
      float scl = ((g >> 6) == 2) ? (2.f * LOG2E) : (-LOG2E);
      float v = ldw(bv, g, mode);
      if (r > 0) v += ldw(Wih, g * NI + (r - 1), mode);
      L.table[r * TROW + (g & 63) * 4 + (g >> 6)] = scl * v;
    }
    // ---- W_hh B-fragments: n=lane&15 -> gate col (unit 16w+l, type tt), k=q*8+j ----
    f16x8 Bf[4][2];
#pragma unroll
    for (int tt = 0; tt < 4; ++tt) {
      float scl = (tt == 2) ? (2.f * LOG2E) : (-LOG2E);
      int g = 64 * tt + 16 * w + l;
#pragma unroll
      for (int kc = 0; kc < 2; ++kc) {
        f16x8 v;
#pragma unroll
        for (int j = 0; j < 8; ++j)
          v[j] = (f16)(scl * ldw(Whh, g * HH + kc * 32 + q * 8 + j, mode));
        Bf[tt][kc] = v;
      }
    }
    for (int idx = t; idx < 2 * MB4 * PAD; idx += 256)
      ((f16*)L.hbuf)[idx] = (f16)0.f;
    __syncthreads();

    float d_st = 0.f, hlast = 0.f;   // d = 2*log2e*c
    int jj = 16 * w + l;

    // x-pipeline prologue: wx for s=0 (regs), tok for s=1 (reg)
    f32x4 wxc;
    {
      int pos0 = dir ? (SS - 1) : 0;
      wxc = *(const f32x4*)&L.table[(int)L.tok_s[pos0 * MB4 + q] * TROW + jj * 4];
    }
    int tok1;
    {
      int pos1 = dir ? (SS - 2) : 1;
      tok1 = (int)L.tok_s[pos1 * MB4 + q];
    }

    const f32x4 Z = {0.f, 0.f, 0.f, 0.f};

#pragma unroll 2
    for (int s = 0; s < SS; ++s) {
      int p = s & 1;
      // critical path: h fragments (A[m=l][k=q*8+j] = h[bsel][k], 4x dup rows)
      f16x8 a0 = *(const f16x8*)&L.hbuf[p][bsel][q * 8];
      f16x8 a1 = *(const f16x8*)&L.hbuf[p][bsel][32 + q * 8];
      // off-path: wx prefetch for s+1 (single b128), tok fetch for s+2
      f32x4 wxn = *(const f32x4*)&L.table[tok1 * TROW + jj * 4];
      {
        int pos2 = (dir ? (SS - 3 - s) : (s + 2)) & (SS - 1);  // wrapped values unused
        tok1 = (int)L.tok_s[pos2 * MB4 + q];
      }

      // parallel-K MFMA pair per gate type (zero-C hoisted; one dependent MFMA
      // latency removed from the pole; gates assembled by scalar adds)
      f32x4 accA[4], accB[4];
#pragma unroll
      for (int tt = 0; tt < 4; ++tt)
        accA[tt] = __builtin_amdgcn_mfma_f32_16x16x32_f16(a0, Bf[tt][0], Z, 0, 0, 0);
#pragma unroll
      for (int tt = 0; tt < 4; ++tt)
        accB[tt] = __builtin_amdgcn_mfma_f32_16x16x32_f16(a1, Bf[tt][1], Z, 0, 0, 0);

      float g_i = accA[0][0] + accB[0][0] + wxc[0];
      float g_f = accA[1][0] + accB[1][0] + wxc[1];
      float g_g = accA[2][0] + accB[2][0] + wxc[2];
      float g_o = accA[3][0] + accB[3][0] + wxc[3];

      // d-state activation: Ei=e^-i, Ef=e^-f, Eo=e^-o, G=e^2g; F=sigma(f);
      // Itg=sigma(i)*tanh(g); d' = F*d + 2log2e*Itg; h = tanh(c)*sigma(o)
      {
        float Ei = fexp2(g_i);
        float Ef = fexp2(g_f);
        float G  = fexp2(g_g);
        float Eo = fexp2(g_o);
        float F   = frcp(Ef + 1.f);
        float Itg = (G - 1.f) * frcp((Ei + 1.f) * (G + 1.f));
        float dnew = fmaf(F, d_st, (2.f * LOG2E) * Itg);
        d_st = dnew;
        float C = fexp2(dnew);
        float hv = (C - 1.f) * frcp((Eo + 1.f) * (C + 1.f));
        hlast = hv;
        L.hbuf[p ^ 1][q][jj] = (f16)hv;
      }
      __syncthreads();
      wxc = wxn;
    }
    hout[(b0 + q) * 128 + dir * 64 + jj] = hlast;

    // ---- publish + elect the last finisher of this group ----
    __threadfence();
    __syncthreads();
    if (t == 0) {
      int old = __hip_atomic_fetch_add(&cnt[bx & 127], 1,
                                       __ATOMIC_ACQ_REL, __HIP_MEMORY_SCOPE_AGENT);
      elect_sh = (old == 1);
    }
    __syncthreads();
    if (!elect_sh) return;

    // ================= fc tail (second finisher only; chain already done) ======
    auto& F = sh.f;   // overlays dead lstm tables
    // c2 flags were released ~250 us ago by the conv blocks; poll expected 0 iters
    if (t < 4) {
      while (__hip_atomic_load(&c2f[b0 + t], __ATOMIC_ACQUIRE,
                               __HIP_MEMORY_SCOPE_AGENT) == 0)
        __builtin_amdgcn_s_sleep(8);
    }
    __syncthreads();
    __threadfence();

    for (int i = t; i < 4 * 228; i += 256) {
      int m = i / 228, k = i - m * 228;
      F.merged[m][k] = (k < 128) ? hout[(b0 + m) * 128 + k]
                                 : c2g[(b0 + m) * 100 + (k - 128)];
    }
    __syncthreads();
    // fc1: t -> (batch m = t>>6, out o = t&63), 228-MAC dot from LDS (broadcast reads)
    {
      int m = t >> 6, o = t & 63;
      float v = ldw(fc1_b, o, mode);
#pragma unroll 4
      for (int k = 0; k < 228; ++k)
        v = fmaf(F.merged[m][k], ldw(fc1_w, o * 228 + k, mode), v);
      F.fc1v[m][o] = v;
    }
    __syncthreads();
    if (t < 8) {
      int m = t >> 1, o = t & 1;
      float v = ldw(fc2_b, o, mode);
#pragma unroll 4
      for (int k = 0; k < 64; ++k)
        v = fmaf(F.fc1v[m][k], ldw(fc2_w, o * 64 + k, mode), v);
      F.f2[m][o] = v;
    }
    __syncthreads();
    if (t < 4) {
      float x0 = F.f2[t][0], x1 = F.f2[t][1];
      float mx = fmaxf(x0, x1);
      float e0 = fexp2(LOG2E * (x0 - mx)), e1 = fexp2(LOG2E * (x1 - mx));
      float inv = frcp(e0 + e1);
      if (mode) {
        ((__hip_bfloat16*)out)[(b0 + t) * 2 + 0] = __float2bfloat16(e0 * inv);
        ((__hip_bfloat16*)out)[(b0 + t) * 2 + 1] = __float2bfloat16(e1 * inv);
      } else {
        ((float*)out)[(b0 + t) * 2 + 0] = e0 * inv;
        ((float*)out)[(b0 + t) * 2 + 1] = e1 * inv;
      }
    }

  } else {
    // ================= conv branch (one batch; r9-verified; exits when done) =====
    auto& C = sh.c;
    int b = bx - 256;
    // own extraction: plain tok per position + len
    int cnt2 = 0;
    if (mode) {
      for (int k0 = 0; k0 < 4; ++k0) {
        const u32* src = (const u32*)in1 + ((size_t)b * SS + k0 * 256) * 10;
#pragma unroll
        for (int i = 0; i < 10; ++i) C.stg[t + i * 256] = src[t + i * 256];  // coalesced
        __syncthreads();
        const u32* row = C.stg + t * 10;
        int tok = -1;
#pragma unroll
        for (int ww = 0; ww < 10; ++ww) {
          u32 u = row[ww];
          if (u & 0xFFFFu) tok = 2 * ww;
          if (u >> 16)     tok = 2 * ww + 1;
        }
        C.tok_c[k0 * 256 + t] = (short)tok;
        cnt2 += (tok >= 0);
        __syncthreads();
      }
    } else {
      float4* st = (float4*)C.stg;
      for (int k0 = 0; k0 < 4; ++k0) {
        const float4* src = (const float4*)((const float*)in1 + ((size_t)b * SS + k0 * 256) * 20);
#pragma unroll
        for (int i = 0; i < 5; ++i) st[t + i * 256] = src[t + i * 256];  // coalesced 16B/lane
        __syncthreads();
        const float* row = (const float*)C.stg + t * 20;
        int tok = -1;
#pragma unroll
        for (int ww = 0; ww < 20; ++ww)
          if (row[ww] != 0.f) tok = ww;
        C.tok_c[k0 * 256 + t] = (short)tok;
        cnt2 += (tok >= 0);
        __syncthreads();
      }
    }
    C.redc[t] = cnt2;
    __syncthreads();
    for (int stp = 128; stp > 0; stp >>= 1) {
      if (t < stp) C.redc[t] += C.redc[t + stp];
      __syncthreads();
    }
    int len = C.redc[0];
    int bw = len >> 2;

    for (int i = t; i < 400; i += 256) C.c1w[i] = ldw(conv1_w, i, mode);
    __syncthreads();

    // ragged 4-bin mean: 240 threads = 80 (k,cc) units x 3 segments
    if (t < 240) {
      int seg = t / 80;
      int u = t - seg * 80;
      int k = u / 20, cc = u % 20;
      int base = k * bw;
      int s0 = base + (seg * bw) / 3;
      int s1 = base + ((seg + 1) * bw) / 3;
      float p0 = 0.f, p1 = 0.f, p2 = 0.f, p3 = 0.f;
      int s = s0;
      for (; s + 4 <= s1; s += 4) {
        // faithful torch reshape: flat f = s*20+cc of the [20,1024] map
        int f0 = s * 20 + cc, f1 = f0 + 20, f2 = f0 + 40, f3 = f0 + 60;
        int tk0 = C.tok_c[f0 & 1023];
        int tk1 = C.tok_c[f1 & 1023];
        int tk2 = C.tok_c[f2 & 1023];
        int tk3 = C.tok_c[f3 & 1023];
        if (tk0 >= 0) p0 += C.c1w[(f0 >> 10) * 20 + tk0];
        if (tk1 >= 0) p1 += C.c1w[(f1 >> 10) * 20 + tk1];
        if (tk2 >= 0) p2 += C.c1w[(f2 >> 10) * 20 + tk2];
        if (tk3 >= 0) p3 += C.c1w[(f3 >> 10) * 20 + tk3];
      }
      for (; s < s1; ++s) {
        int f = s * 20 + cc;
        int tk = C.tok_c[f & 1023];
        if (tk >= 0) p0 += C.c1w[(f >> 10) * 20 + tk];
      }
      C.pav[seg][u] = (p0 + p1) + (p2 + p3);
    }
    __syncthreads();
    if (t < 80) C.avg[t] = (C.pav[0][t] + C.pav[1][t] + C.pav[2][t]) / (float)bw;
    __syncthreads();

    // conv2: 200 threads = 100 outputs x 2 K-halves of 40
    if (t < 200) {
      int half = t / 100, o = t - half * 100;
      float dot = 0.f;
      int q0 = half * 40;
#pragma unroll 8
      for (int q = q0; q < q0 + 40; ++q)
        dot = fmaf(C.avg[q], ldw(conv2_w, o * 80 + q, mode), dot);
      C.cpart[half][o] = dot;
    }
    __syncthreads();
    if (t < 100) {
      float dot = C.cpart[0][t] + C.cpart[1][t] + ldw(conv2_b, t, mode);
      c2g[b * 100 + t] = dot > 0.f ? dot : 0.f;  // relu'd, biased
    }
    // release the per-batch c2 flag, then exit (CU freed)
    __threadfence();
    __syncthreads();
    if (t == 0)
      __hip_atomic_store(&c2f[b], 1, __ATOMIC_RELEASE, __HIP_MEMORY_SCOPE_AGENT);
  }
}

extern "C" void kernel_launch(void* const* d_in, const int* in_sizes, int n_in,
                              void* d_out, int out_size, void* d_ws, size_t ws_size,
                              hipStream_t stream) {
  (void)in_sizes; (void)n_in; (void)out_size; (void)ws_size;
  char* ws = (char*)d_ws;
  int*   c2f  = (int*)ws;                                    // 2 KB (512 ints)
  int*   cnt  = (int*)(ws + 2048);                           // 512 B (128 ints)
  float* hout = (float*)(ws + 4096);                         // 256 KB
  float* c2g  = (float*)(ws + 4096 + (size_t)BB * 128 * 4);  // 200 KB

  hipMemsetAsync(ws, 0, 4096, stream);                       // capture-safe
  lstm_kernel<<<768, 256, 0, stream>>>(d_in[0],
                                       d_in[1], d_in[2], d_in[3],
                                       d_in[4], d_in[5], d_in[6],
                                       d_in[7], d_in[8], d_in[9],
                                       d_in[10], d_in[11], d_in[12], d_in[13],
                                       c2f, cnt, hout, c2g, d_out);
}

// Round 12
// 438.169 us; speedup vs baseline: 1.1274x; 1.0043x over previous
//
#include <hip/hip_runtime.h>
#include <hip/hip_bf16.h>

#define BB 512
#define SS 1024
#define NI 20
#define HH 64
#define NG 256   // 4*H
#define MB4 4    // batch-dirs per lstm block (1 cell per lane)
#define PAD 80   // h-row stride in f16
#define TROW 260 // x-table row stride (floats); [tok][unit][4tt], 16B rows
#define WST 230  // fc1 LDS weight row stride (u16); 115 mod 32 coprime -> bank-free

typedef unsigned short u16;
typedef unsigned int u32;
typedef unsigned long long u64;
typedef _Float16 f16;
typedef f16 f16x8 __attribute__((ext_vector_type(8)));
typedef float f32x4 __attribute__((ext_vector_type(4)));

#define LOG2E 1.4426950408889634f

__device__ __forceinline__ float bf2f(u16 b) { return __uint_as_float(((u32)b) << 16); }
// mode==1: data is bf16; mode==0: data is fp32
__device__ __forceinline__ float ldw(const void* p, int idx, int mode) {
  return mode ? bf2f(((const u16*)p)[idx]) : ((const float*)p)[idx];
}
__device__ __forceinline__ float frcp(float x) { return __builtin_amdgcn_rcpf(x); }
__device__ __forceinline__ float fexp2(float x) { return __builtin_amdgcn_exp2f(x); }

// ---- SINGLE kernel, last-finisher election (r11 structure verbatim -- loop
// codegen proven unperturbed: VGPR 48, issue cycles == r9). r11 diagnosis:
// the 87 us tail == fc1's UNCOALESCED weight reads (64 lanes x 64 distinct
// cache lines per instr, ~7.5M transactions -- the same traffic that was the
// "81 us rest" of r8/r9's separate head kernel; never launch gap). Fix here:
// in bf16 mode the elected block stages fc1_w into LDS COALESCED (consecutive
// threads -> consecutive u16; ~57 x 128B/wave rounds) at row stride 230 u16
// (dword 115o mod 32, gcd(115,32)=1 -> 64 lanes spread all 32 banks -> free),
// then the 228-MAC dots read LDS. fp32 mode keeps the legacy scalar path.
// blocks 0..255 = BiLSTM (r9-verbatim loop); 256..767 = conv path, writes c2g
// + flag, EXITS. Second lstm finisher per group runs the fc tail (chain done
// -> zero wall cost). Weights prescaled: i,f,o by -log2e, g by +2log2e.
union __align__(16) SharedU {
  struct __align__(16) {                 // ---- lstm branch (~31.3 KB)
    float table[21 * TROW];              // 21.8 KB; doubles as extract staging
    f16 hbuf[2][MB4][PAD];
    short tok_s[SS * MB4];               // [pos][m], stores tok+1
  } l;
  struct __align__(16) {                 // ---- conv branch (~27.2 KB)
    u32 stg[5120];                       // 20 KB extract staging
    float c1w[400];
    short tok_c[SS];                     // plain tok
    int redc[256];
    float pav[3][80];
    float avg[80];
    float cpart[2][100];
  } c;
  struct __align__(16) {                 // ---- fc epilogue (~34.2 KB)
    u16 w16[64 * WST];                   // 28.75 KB coalesced-staged fc1_w (bf16 mode)
    float merged[4][232];
    float fc1v[4][64];
    float f2[4][2];
  } f;
};

__global__ __launch_bounds__(256)
void lstm_kernel(const void* in1,
                 const void* Wih_f, const void* Whh_f, const void* b_f,
                 const void* Wih_b, const void* Whh_b, const void* b_b,
                 const void* conv1_w, const void* conv2_w, const void* conv2_b,
                 const void* fc1_w, const void* fc1_b,
                 const void* fc2_w, const void* fc2_b,
                 int* c2f, int* cnt, float* hout, float* c2g, void* out) {
  int bx = blockIdx.x;
  int t = threadIdx.x;

  __shared__ SharedU sh;
  __shared__ int mode_sh;
  __shared__ int elect_sh;

  // ---- mode probe: b_f read as bf16; fp32 shows wild exponents ----
  if (t == 0) mode_sh = 1;
  __syncthreads();
  {
    float v = bf2f(((const u16*)b_f)[t]);
    if (!(fabsf(v) < 1000.0f)) atomicAnd(&mode_sh, 0);
  }
  __syncthreads();
  int mode = mode_sh;

  if (bx < 256) {
    // ================= LSTM branch (r9 verbatim) =================
    auto& L = sh.l;
    int dir = bx >> 7;
    int b0 = (bx & 127) * MB4;
    int w = t >> 6, lane = t & 63, l = lane & 15, q = lane >> 4;
    int bsel = l >> 2;            // batch whose h this lane's A-row carries
    const void* Wih = dir ? Wih_b : Wih_f;
    const void* Whh = dir ? Whh_b : Whh_f;
    const void* bv  = dir ? b_b   : b_f;

    // ---- token extraction for this block's 4 batches (staged through table) ----
    for (int m = 0; m < MB4; ++m) {
      if (mode) {
        u32* st = (u32*)L.table;
        for (int k0 = 0; k0 < 4; ++k0) {
          const u32* src = (const u32*)in1 + ((size_t)(b0 + m) * SS + k0 * 256) * 10;
#pragma unroll
          for (int i = 0; i < 10; ++i) st[t + i * 256] = src[t + i * 256];  // coalesced
          __syncthreads();
          const u32* row = st + t * 10;
          int tok = -1;
#pragma unroll
          for (int ww = 0; ww < 10; ++ww) {
            u32 u = row[ww];
            if (u & 0xFFFFu) tok = 2 * ww;
            if (u >> 16)     tok = 2 * ww + 1;
          }
          L.tok_s[(k0 * 256 + t) * MB4 + m] = (short)(tok + 1);
          __syncthreads();
        }
      } else {
        float4* st = (float4*)L.table;
        for (int k0 = 0; k0 < 4; ++k0) {
          const float4* src = (const float4*)((const float*)in1 + ((size_t)(b0 + m) * SS + k0 * 256) * 20);
#pragma unroll
          for (int i = 0; i < 5; ++i) st[t + i * 256] = src[t + i * 256];  // coalesced 16B/lane
          __syncthreads();
          const float* row = (const float*)L.table + t * 20;
          int tok = -1;
#pragma unroll
          for (int ww = 0; ww < 20; ++ww)
            if (row[ww] != 0.f) tok = ww;
          L.tok_s[(k0 * 256 + t) * MB4 + m] = (short)(tok + 1);
          __syncthreads();
        }
      }
    }

    // ---- x-projection table: table[tok+1][u][tt] = scl_tt*(W_ih[64tt+u][tok]+b); row 0 = bias ----
    for (int idx = t; idx < 21 * 256; idx += 256) {
      int r = idx >> 8, g = idx & 255;
      float scl = ((g >> 6) == 2) ? (2.f * LOG2E) : (-LOG2E);
      float v = ldw(bv, g, mode);
      if (r > 0) v += ldw(Wih, g * NI + (r - 1), mode);
      L.table[r * TROW + (g & 63) * 4 + (g >> 6)] = scl * v;
    }
    // ---- W_hh B-fragments: n=lane&15 -> gate col (unit 16w+l, type tt), k=q*8+j ----
    f16x8 Bf[4][2];
#pragma unroll
    for (int tt = 0; tt < 4; ++tt) {
      float scl = (tt == 2) ? (2.f * LOG2E) : (-LOG2E);
      int g = 64 * tt + 16 * w + l;
#pragma unroll
      for (int kc = 0; kc < 2; ++kc) {
        f16x8 v;
#pragma unroll
        for (int j = 0; j < 8; ++j)
          v[j] = (f16)(scl * ldw(Whh, g * HH + kc * 32 + q * 8 + j, mode));
        Bf[tt][kc] = v;
      }
    }
    for (int idx = t; idx < 2 * MB4 * PAD; idx += 256)
      ((f16*)L.hbuf)[idx] = (f16)0.f;
    __syncthreads();

    float d_st = 0.f, hlast = 0.f;   // d = 2*log2e*c
    int jj = 16 * w + l;

    // x-pipeline prologue: wx for s=0 (regs), tok for s=1 (reg)
    f32x4 wxc;
    {
      int pos0 = dir ? (SS - 1) : 0;
      wxc = *(const f32x4*)&L.table[(int)L.tok_s[pos0 * MB4 + q] * TROW + jj * 4];
    }
    int tok1;
    {
      int pos1 = dir ? (SS - 2) : 1;
      tok1 = (int)L.tok_s[pos1 * MB4 + q];
    }

    const f32x4 Z = {0.f, 0.f, 0.f, 0.f};

#pragma unroll 2
    for (int s = 0; s < SS; ++s) {
      int p = s & 1;
      // critical path: h fragments (A[m=l][k=q*8+j] = h[bsel][k], 4x dup rows)
      f16x8 a0 = *(const f16x8*)&L.hbuf[p][bsel][q * 8];
      f16x8 a1 = *(const f16x8*)&L.hbuf[p][bsel][32 + q * 8];
      // off-path: wx prefetch for s+1 (single b128), tok fetch for s+2
      f32x4 wxn = *(const f32x4*)&L.table[tok1 * TROW + jj * 4];
      {
        int pos2 = (dir ? (SS - 3 - s) : (s + 2)) & (SS - 1);  // wrapped values unused
        tok1 = (int)L.tok_s[pos2 * MB4 + q];
      }

      // parallel-K MFMA pair per gate type (zero-C hoisted; one dependent MFMA
      // latency removed from the pole; gates assembled by scalar adds)
      f32x4 accA[4], accB[4];
#pragma unroll
      for (int tt = 0; tt < 4; ++tt)
        accA[tt] = __builtin_amdgcn_mfma_f32_16x16x32_f16(a0, Bf[tt][0], Z, 0, 0, 0);
#pragma unroll
      for (int tt = 0; tt < 4; ++tt)
        accB[tt] = __builtin_amdgcn_mfma_f32_16x16x32_f16(a1, Bf[tt][1], Z, 0, 0, 0);

      float g_i = accA[0][0] + accB[0][0] + wxc[0];
      float g_f = accA[1][0] + accB[1][0] + wxc[1];
      float g_g = accA[2][0] + accB[2][0] + wxc[2];
      float g_o = accA[3][0] + accB[3][0] + wxc[3];

      // d-state activation: Ei=e^-i, Ef=e^-f, Eo=e^-o, G=e^2g; F=sigma(f);
      // Itg=sigma(i)*tanh(g); d' = F*d + 2log2e*Itg; h = tanh(c)*sigma(o)
      {
        float Ei = fexp2(g_i);
        float Ef = fexp2(g_f);
        float G  = fexp2(g_g);
        float Eo = fexp2(g_o);
        float F   = frcp(Ef + 1.f);
        float Itg = (G - 1.f) * frcp((Ei + 1.f) * (G + 1.f));
        float dnew = fmaf(F, d_st, (2.f * LOG2E) * Itg);
        d_st = dnew;
        float C = fexp2(dnew);
        float hv = (C - 1.f) * frcp((Eo + 1.f) * (C + 1.f));
        hlast = hv;
        L.hbuf[p ^ 1][q][jj] = (f16)hv;
      }
      __syncthreads();
      wxc = wxn;
    }
    hout[(b0 + q) * 128 + dir * 64 + jj] = hlast;

    // ---- publish + elect the last finisher of this group ----
    __threadfence();
    __syncthreads();
    if (t == 0) {
      int old = __hip_atomic_fetch_add(&cnt[bx & 127], 1,
                                       __ATOMIC_ACQ_REL, __HIP_MEMORY_SCOPE_AGENT);
      elect_sh = (old == 1);
    }
    __syncthreads();
    if (!elect_sh) return;

    // ================= fc tail (second finisher only; chain already done) ======
    auto& F = sh.f;   // overlays dead lstm tables
    // c2 flags were released ~250 us ago by the conv blocks; poll expected 0 iters
    if (t < 4) {
      while (__hip_atomic_load(&c2f[b0 + t], __ATOMIC_ACQUIRE,
                               __HIP_MEMORY_SCOPE_AGENT) == 0)
        __builtin_amdgcn_s_sleep(8);
    }
    __syncthreads();
    __threadfence();

    for (int i = t; i < 4 * 228; i += 256) {
      int m = i / 228, k = i - m * 228;
      F.merged[m][k] = (k < 128) ? hout[(b0 + m) * 128 + k]
                                 : c2g[(b0 + m) * 100 + (k - 128)];
    }
    if (mode) {
      // coalesced stage: consecutive t -> consecutive u16 of fc1_w (128B/wave)
      const u16* wsrc = (const u16*)fc1_w;
      for (int i = t; i < 64 * 228; i += 256) {
        int o = i / 228, k = i - o * 228;
        F.w16[o * WST + k] = wsrc[i];
      }
    }
    __syncthreads();
    // fc1: t -> (batch m = t>>6, out o = t&63); weights from LDS (bank-free
    // stride), merged[m][k] wave-uniform broadcast
    {
      int m = t >> 6, o = t & 63;
      float v = ldw(fc1_b, o, mode);
      if (mode) {
        const u16* wr = &F.w16[o * WST];
#pragma unroll 4
        for (int k = 0; k < 228; ++k)
          v = fmaf(bf2f(wr[k]), F.merged[m][k], v);
      } else {
        const float* wr = (const float*)fc1_w + o * 228;
#pragma unroll 4
        for (int k = 0; k < 228; ++k)
          v = fmaf(wr[k], F.merged[m][k], v);
      }
      F.fc1v[m][o] = v;
    }
    __syncthreads();
    if (t < 8) {
      int m = t >> 1, o = t & 1;
      float v = ldw(fc2_b, o, mode);
#pragma unroll 4
      for (int k = 0; k < 64; ++k)
        v = fmaf(F.fc1v[m][k], ldw(fc2_w, o * 64 + k, mode), v);
      F.f2[m][o] = v;
    }
    __syncthreads();
    if (t < 4) {
      float x0 = F.f2[t][0], x1 = F.f2[t][1];
      float mx = fmaxf(x0, x1);
      float e0 = fexp2(LOG2E * (x0 - mx)), e1 = fexp2(LOG2E * (x1 - mx));
      float inv = frcp(e0 + e1);
      if (mode) {
        ((__hip_bfloat16*)out)[(b0 + t) * 2 + 0] = __float2bfloat16(e0 * inv);
        ((__hip_bfloat16*)out)[(b0 + t) * 2 + 1] = __float2bfloat16(e1 * inv);
      } else {
        ((float*)out)[(b0 + t) * 2 + 0] = e0 * inv;
        ((float*)out)[(b0 + t) * 2 + 1] = e1 * inv;
      }
    }

  } else {
    // ================= conv branch (one batch; r9-verified; exits when done) =====
    auto& C = sh.c;
    int b = bx - 256;
    // own extraction: plain tok per position + len
    int cnt2 = 0;
    if (mode) {
      for (int k0 = 0; k0 < 4; ++k0) {
        const u32* src = (const u32*)in1 + ((size_t)b * SS + k0 * 256) * 10;
#pragma unroll
        for (int i = 0; i < 10; ++i) C.stg[t + i * 256] = src[t + i * 256];  // coalesced
        __syncthreads();
        const u32* row = C.stg + t * 10;
        int tok = -1;
#pragma unroll
        for (int ww = 0; ww < 10; ++ww) {
          u32 u = row[ww];
          if (u & 0xFFFFu) tok = 2 * ww;
          if (u >> 16)     tok = 2 * ww + 1;
        }
        C.tok_c[k0 * 256 + t] = (short)tok;
        cnt2 += (tok >= 0);
        __syncthreads();
      }
    } else {
      float4* st = (float4*)C.stg;
      for (int k0 = 0; k0 < 4; ++k0) {
        const float4* src = (const float4*)((const float*)in1 + ((size_t)b * SS + k0 * 256) * 20);
#pragma unroll
        for (int i = 0; i < 5; ++i) st[t + i * 256] = src[t + i * 256];  // coalesced 16B/lane
        __syncthreads();
        const float* row = (const float*)C.stg + t * 20;
        int tok = -1;
#pragma unroll
        for (int ww = 0; ww < 20; ++ww)
          if (row[ww] != 0.f) tok = ww;
        C.tok_c[k0 * 256 + t] = (short)tok;
        cnt2 += (tok >= 0);
        __syncthreads();
      }
    }
    C.redc[t] = cnt2;
    __syncthreads();
    for (int stp = 128; stp > 0; stp >>= 1) {
      if (t < stp) C.redc[t] += C.redc[t + stp];
      __syncthreads();
    }
    int len = C.redc[0];
    int bw = len >> 2;

    for (int i = t; i < 400; i += 256) C.c1w[i] = ldw(conv1_w, i, mode);
    __syncthreads();

    // ragged 4-bin mean: 240 threads = 80 (k,cc) units x 3 segments
    if (t < 240) {
      int seg = t / 80;
      int u = t - seg * 80;
      int k = u / 20, cc = u % 20;
      int base = k * bw;
      int s0 = base + (seg * bw) / 3;
      int s1 = base + ((seg + 1) * bw) / 3;
      float p0 = 0.f, p1 = 0.f, p2 = 0.f, p3 = 0.f;
      int s = s0;
      for (; s + 4 <= s1; s += 4) {
        // faithful torch reshape: flat f = s*20+cc of the [20,1024] map
        int f0 = s * 20 + cc, f1 = f0 + 20, f2 = f0 + 40, f3 = f0 + 60;
        int tk0 = C.tok_c[f0 & 1023];
        int tk1 = C.tok_c[f1 & 1023];
        int tk2 = C.tok_c[f2 & 1023];
        int tk3 = C.tok_c[f3 & 1023];
        if (tk0 >= 0) p0 += C.c1w[(f0 >> 10) * 20 + tk0];
        if (tk1 >= 0) p1 += C.c1w[(f1 >> 10) * 20 + tk1];
        if (tk2 >= 0) p2 += C.c1w[(f2 >> 10) * 20 + tk2];
        if (tk3 >= 0) p3 += C.c1w[(f3 >> 10) * 20 + tk3];
      }
      for (; s < s1; ++s) {
        int f = s * 20 + cc;
        int tk = C.tok_c[f & 1023];
        if (tk >= 0) p0 += C.c1w[(f >> 10) * 20 + tk];
      }
      C.pav[seg][u] = (p0 + p1) + (p2 + p3);
    }
    __syncthreads();
    if (t < 80) C.avg[t] = (C.pav[0][t] + C.pav[1][t] + C.pav[2][t]) / (float)bw;
    __syncthreads();

    // conv2: 200 threads = 100 outputs x 2 K-halves of 40
    if (t < 200) {
      int half = t / 100, o = t - half * 100;
      float dot = 0.f;
      int q0 = half * 40;
#pragma unroll 8
      for (int q = q0; q < q0 + 40; ++q)
        dot = fmaf(C.avg[q], ldw(conv2_w, o * 80 + q, mode), dot);
      C.cpart[half][o] = dot;
    }
    __syncthreads();
    if (t < 100) {
      float dot = C.cpart[0][t] + C.cpart[1][t] + ldw(conv2_b, t, mode);
      c2g[b * 100 + t] = dot > 0.f ? dot : 0.f;  // relu'd, biased
    }
    // release the per-batch c2 flag, then exit (CU freed)
    __threadfence();
    __syncthreads();
    if (t == 0)
      __hip_atomic_store(&c2f[b], 1, __ATOMIC_RELEASE, __HIP_MEMORY_SCOPE_AGENT);
  }
}

extern "C" void kernel_launch(void* const* d_in, const int* in_sizes, int n_in,
                              void* d_out, int out_size, void* d_ws, size_t ws_size,
                              hipStream_t stream) {
  (void)in_sizes; (void)n_in; (void)out_size; (void)ws_size;
  char* ws = (char*)d_ws;
  int*   c2f  = (int*)ws;                                    // 2 KB (512 ints)
  int*   cnt  = (int*)(ws + 2048);                           // 512 B (128 ints)
  float* hout = (float*)(ws + 4096);                         // 256 KB
  float* c2g  = (float*)(ws + 4096 + (size_t)BB * 128 * 4);  // 200 KB

  hipMemsetAsync(ws, 0, 4096, stream);                       // capture-safe
  lstm_kernel<<<768, 256, 0, stream>>>(d_in[0],
                                       d_in[1], d_in[2], d_in[3],
                                       d_in[4], d_in[5], d_in[6],
                                       d_in[7], d_in[8], d_in[9],
                                       d_in[10], d_in[11], d_in[12], d_in[13],
                                       c2f, cnt, hout, c2g, d_out);
}